// Round 1
// baseline (458.036 us; speedup 1.0000x reference)
//
#include <hip/hip_runtime.h>

// LSSViewTransform: 1x1 conv (context channels only; mean(softmax)==1/64
// identity) + bilinear resize (32,88)->(432,496), half-pixel centers.

#define K_IN    256
#define C_CTX   128
#define C_DEPTH 64
#define H_IN    32
#define W_IN    88
#define POS     (H_IN * W_IN)     // 2816 = 44 * 64
#define H_OUT   432
#define W_OUT   496
#define XG      (W_OUT / 4)       // 124 float4 groups per output row
#define GPP     (XG * H_OUT)      // 53568 groups per (b,c) plane
#define NPLANE  (4 * C_CTX)       // 512 planes
#define KC      64                // k-chunk

#define PPT     4                 // planes per thread (resize)
#define GY      (NPLANE / PPT)    // 128 plane-groups
#define GX      ((GPP + 255) / 256)  // 210 spatial blocks per plane-group
#define NBLK    (GX * GY)         // 26880 (divisible by 8)
#define CHUNK   (NBLK / 8)        // 3360 blocks per XCD

typedef float f32x4 __attribute__((ext_vector_type(4)));

// ---------------------------------------------------------------------------
// Kernel 1: ctx[b][c][pos] = (sum_i feat[b][i][pos]*Wc[64+c][i] + bc[64+c])/64
// LDS-LDS register-blocked GEMM, tile 64 pos x 64 ch, 256 thr.
// NEW: register-prefetch pipeline — next kc's global loads are issued into
// VGPRs right after the barrier, so ~1000cy HBM/L2 latency hides under the
// 64-step FMA loop (occupancy is only ~1.4 blocks/CU; TLP can't hide it).
// ---------------------------------------------------------------------------
__global__ __launch_bounds__(256) void conv1x1_kernel(
    const float* __restrict__ feat, const float* __restrict__ Wc,
    const float* __restrict__ bc, float* __restrict__ ctx)
{
    __shared__ float As[KC * 64];   // [k][pos]  16 KB
    __shared__ float Bs[KC * 64];   // [k][ch]   16 KB

    const int t       = threadIdx.x;
    const int posbase = blockIdx.x * 64;
    const int cbase   = blockIdx.y * 64;
    const int b       = blockIdx.z;

    const int pg = t & 15;          // this thread's pos group (4 pos)
    const int cg = t >> 4;          // this thread's ch group (4 ch)

    const float* fb = feat + (size_t)b * K_IN * POS + posbase;
    const float* wb = Wc + (size_t)(C_DEPTH + cbase) * K_IN;

    // staging lane roles (same addressing as before, hoisted)
    const int ka  = t >> 4;         // A: k-row base, pa: 4-pos offset
    const int pa  = (t & 15) * 4;
    const int chB = t >> 2;         // B: channel row
    const int kB  = (t & 3) * 4;    // B: k base within 16-group

    float4 rA[4], rB[4];
    #pragma unroll
    for (int j = 0; j < 4; ++j) {
        rA[j] = *(const float4*)(fb + (size_t)(ka + 16 * j) * POS + pa);
        rB[j] = *(const float4*)(wb + (size_t)chB * K_IN + kB + 16 * j);
    }

    float acc[4][4];
    #pragma unroll
    for (int i = 0; i < 4; ++i)
        #pragma unroll
        for (int j = 0; j < 4; ++j) acc[i][j] = 0.f;

    for (int kc = 0; kc < K_IN / KC; ++kc) {
        // ---- LDS write from staged registers ----
        #pragma unroll
        for (int j = 0; j < 4; ++j) {
            *(float4*)&As[(ka + 16 * j) * 64 + pa] = rA[j];
            Bs[(kB + 0 + 16 * j) * 64 + chB] = rB[j].x;
            Bs[(kB + 1 + 16 * j) * 64 + chB] = rB[j].y;
            Bs[(kB + 2 + 16 * j) * 64 + chB] = rB[j].z;
            Bs[(kB + 3 + 16 * j) * 64 + chB] = rB[j].w;
        }
        __syncthreads();

        // ---- issue next kc's global loads (overlap with FMA loop) ----
        if (kc < K_IN / KC - 1) {
            #pragma unroll
            for (int j = 0; j < 4; ++j) {
                rA[j] = *(const float4*)(fb +
                        (size_t)((kc + 1) * KC + ka + 16 * j) * POS + pa);
                rB[j] = *(const float4*)(wb + (size_t)chB * K_IN +
                        (kc + 1) * KC + kB + 16 * j);
            }
        }

        // ---- compute: 64 k-steps, 2 b128 + 16 FMA each ----
        #pragma unroll 8
        for (int k = 0; k < KC; ++k) {
            float4 a = *(const float4*)&As[k * 64 + pg * 4];
            float4 w = *(const float4*)&Bs[k * 64 + cg * 4];
            acc[0][0] = fmaf(a.x, w.x, acc[0][0]);
            acc[1][0] = fmaf(a.y, w.x, acc[1][0]);
            acc[2][0] = fmaf(a.z, w.x, acc[2][0]);
            acc[3][0] = fmaf(a.w, w.x, acc[3][0]);
            acc[0][1] = fmaf(a.x, w.y, acc[0][1]);
            acc[1][1] = fmaf(a.y, w.y, acc[1][1]);
            acc[2][1] = fmaf(a.z, w.y, acc[2][1]);
            acc[3][1] = fmaf(a.w, w.y, acc[3][1]);
            acc[0][2] = fmaf(a.x, w.z, acc[0][2]);
            acc[1][2] = fmaf(a.y, w.z, acc[1][2]);
            acc[2][2] = fmaf(a.z, w.z, acc[2][2]);
            acc[3][2] = fmaf(a.w, w.z, acc[3][2]);
            acc[0][3] = fmaf(a.x, w.w, acc[0][3]);
            acc[1][3] = fmaf(a.y, w.w, acc[1][3]);
            acc[2][3] = fmaf(a.z, w.w, acc[2][3]);
            acc[3][3] = fmaf(a.w, w.w, acc[3][3]);
        }
        __syncthreads();
    }

    const float s = 1.0f / 64.0f;   // mean over softmax channels == 1/64
    #pragma unroll
    for (int j = 0; j < 4; ++j) {
        int ch = cbase + 4 * cg + j;
        float bb = bc[C_DEPTH + ch];
        float4 r;
        r.x = (acc[0][j] + bb) * s;
        r.y = (acc[1][j] + bb) * s;
        r.z = (acc[2][j] + bb) * s;
        r.w = (acc[3][j] + bb) * s;
        *(float4*)(ctx + (size_t)(b * C_CTX + ch) * POS + posbase + 4 * pg) = r;
    }
}

// ---------------------------------------------------------------------------
// Kernel 2: bilinear resize. NEW structure:
//  - PPT=4 planes per thread: bilinear taps/weights depend only on (y,x) —
//    compute once, reuse for 4 planes (index math amortized 4x).
//  - XCD-chunked remap: 26880 blocks = 8*3360; wg=(bid&7)*CHUNK + bid>>3 puts
//    64 consecutive planes on one XCD -> per-XCD ctx working set 704 KB
//    (L2-resident, fetched once) instead of all XCDs streaming all planes.
//  - Nontemporal stores: 438.8 MB write-once, keep L2 for ctx reads.
// ---------------------------------------------------------------------------
__global__ __launch_bounds__(256) void resize_kernel(
    const float* __restrict__ ctx, float* __restrict__ out)
{
    int bid = blockIdx.x;
    int wg  = (bid & 7) * CHUNK + (bid >> 3);   // bijective XCD-chunk remap
    int pg4 = wg / GX;                          // plane-group 0..127
    int gx  = wg - pg4 * GX;                    // spatial block 0..209

    int g = gx * 256 + threadIdx.x;
    if (g >= GPP) return;
    int y  = g / XG;
    int xg = g - y * XG;
    int plane0 = pg4 * PPT;

    const float SCY = 32.0f / 432.0f;
    const float SCX = 88.0f / 496.0f;

    float sy  = (y + 0.5f) * SCY - 0.5f;
    float fyf = floorf(sy);
    float wy  = sy - fyf;
    int y0  = (int)fyf;
    int y0c = max(y0, 0);
    int y1c = min(y0 + 1, H_IN - 1);
    const int r0o = y0c * W_IN;
    const int r1o = y1c * W_IN;

    float sx0 = (4 * xg + 0.5f) * SCX - 0.5f;
    int xb = (int)floorf(sx0);

    int xt[3];
    #pragma unroll
    for (int tp = 0; tp < 3; ++tp)
        xt[tp] = min(max(xb + tp, 0), W_IN - 1);

    float fx[4];
    int   tj[4];
    #pragma unroll
    for (int j = 0; j < 4; ++j) {
        float s  = (4 * xg + j + 0.5f) * SCX - 0.5f;
        float fs = floorf(s);
        fx[j] = s - fs;
        tj[j] = (int)fs - xb;               // 0 or 1 (monotone fp, safe)
    }

    const float* p = ctx + (size_t)plane0 * POS;
    size_t obase = ((size_t)plane0 * H_OUT + y) * W_OUT + 4 * xg;

    #pragma unroll
    for (int pp = 0; pp < PPT; ++pp) {
        const float* r0 = p + (size_t)pp * POS + r0o;
        const float* r1 = p + (size_t)pp * POS + r1o;
        float ry0, ry1, ry2;
        {
            float a0 = r0[xt[0]], b0 = r1[xt[0]];
            float a1 = r0[xt[1]], b1 = r1[xt[1]];
            float a2 = r0[xt[2]], b2 = r1[xt[2]];
            ry0 = a0 + wy * (b0 - a0);
            ry1 = a1 + wy * (b1 - a1);
            ry2 = a2 + wy * (b2 - a2);
        }
        float o[4];
        #pragma unroll
        for (int j = 0; j < 4; ++j) {
            float lo = (tj[j] == 0) ? ry0 : ry1;   // branch-free selects,
            float hi = (tj[j] == 0) ? ry1 : ry2;   // no runtime array index
            o[j] = lo + fx[j] * (hi - lo);
        }
        f32x4 v = {o[0], o[1], o[2], o[3]};
        __builtin_nontemporal_store(v,
            (f32x4*)(out + obase + (size_t)pp * (H_OUT * W_OUT)));
    }
}

extern "C" void kernel_launch(void* const* d_in, const int* in_sizes, int n_in,
                              void* d_out, int out_size, void* d_ws, size_t ws_size,
                              hipStream_t stream) {
    const float* feat = (const float*)d_in[0];   // (4, 256, 32, 88)
    const float* Wc   = (const float*)d_in[1];   // (192, 256)
    const float* bc   = (const float*)d_in[2];   // (192,)
    float* out = (float*)d_out;                  // (4, 128, 432, 496)
    float* ctx = (float*)d_ws;                   // (4, 128, 2816) = 5.77 MB

    dim3 b1(256);
    dim3 g1(POS / 64, C_CTX / 64, 4);            // (44, 2, 4) = 352 blocks
    conv1x1_kernel<<<g1, b1, 0, stream>>>(feat, Wc, bc, ctx);

    dim3 b2(256);
    dim3 g2(NBLK);                               // 26880 blocks, 1-D
    resize_kernel<<<g2, b2, 0, stream>>>(ctx, out);
}